// Round 4
// baseline (9916.909 us; speedup 1.0000x reference)
//
#include <hip/hip_runtime.h>
#include <stdint.h>

#define H 1024
#define G_ 256
#define LPAD 128
#define GH (G_ * H)

typedef float  floatx4 __attribute__((ext_vector_type(4)));
typedef short  shortx8 __attribute__((ext_vector_type(8)));

#define MFMA(a, b, c) __builtin_amdgcn_mfma_f32_16x16x32_bf16((a), (b), (c), 0, 0, 0)

__device__ __forceinline__ uint16_t f2bf(float f) {
  union { float f; uint32_t i; } v; v.f = f;
  uint32_t r = (v.i + 0x7FFFu + ((v.i >> 16) & 1u)) >> 16;
  return (uint16_t)r;
}
__device__ __forceinline__ float bf2f(uint16_t u) {
  union { uint32_t i; float f; } v; v.i = ((uint32_t)u) << 16; return v.f;
}
__device__ __forceinline__ float sigmoid_(float x) { return 1.f / (1.f + __expf(-x)); }
__device__ __forceinline__ float tanh_(float x) {
  float ax = fabsf(x);
  float e = __expf(2.f * ax);          // overflow -> inf -> t = 1 (correct limit)
  float t = 1.f - 2.f / (e + 1.f);
  return x >= 0.f ? t : -t;
}

// ---------------- fp32 -> bf16 cast, 8 elems/thread ----------------
__global__ void k_f2b(const float* __restrict__ src, uint16_t* __restrict__ dst) {
  size_t i = ((size_t)blockIdx.x * blockDim.x + threadIdx.x) * 8;
  float4 a = *(const float4*)(src + i);
  float4 b = *(const float4*)(src + i + 4);
  uint16_t o[8] = {f2bf(a.x), f2bf(a.y), f2bf(a.z), f2bf(a.w),
                   f2bf(b.x), f2bf(b.y), f2bf(b.z), f2bf(b.w)};
  uint4 ov; __builtin_memcpy(&ov, o, 16);
  *(uint4*)(dst + i) = ov;
}

// ---------------- setup: start[g] binary search + zero barrier flags ----------------
__global__ void k_setup(const int* __restrict__ batch, int N, int* __restrict__ start,
                        int* __restrict__ flags) {
  int g = threadIdx.x;
  if (g < 256) flags[g] = 0;
  if (g > G_) return;
  int lo = 0, hi = N;
  while (lo < hi) { int mid = (lo + hi) >> 1; if (batch[mid] < g) lo = mid + 1; else hi = mid; }
  start[g] = lo;
}

// ---------------- message = relu(h_atom + bias) -> bf16 ----------------
__global__ void k_msg(const float* __restrict__ h_atom, const float* __restrict__ bias,
                      uint16_t* __restrict__ msg) {
  int row = blockIdx.x, t = threadIdx.x;           // 128 threads * 8 elems
  size_t off = (size_t)row * H + t * 8;
  float4 h0 = *(const float4*)(h_atom + off);
  float4 h1 = *(const float4*)(h_atom + off + 4);
  float4 b0 = *(const float4*)(bias + t * 8);
  float4 b1 = *(const float4*)(bias + t * 8 + 4);
  float v[8] = {h0.x + b0.x, h0.y + b0.y, h0.z + b0.z, h0.w + b0.w,
                h1.x + b1.x, h1.y + b1.y, h1.z + b1.z, h1.w + b1.w};
  uint16_t o[8];
#pragma unroll
  for (int i = 0; i < 8; i++) o[i] = f2bf(v[i] > 0.f ? v[i] : 0.f);
  uint4 ov; __builtin_memcpy(&ov, o, 16);
  *(uint4*)(msg + off) = ov;
}

// ---------------- h0 = segment_max(h_atom); fp32 (reg init) + bf16 (A-exchange) ------
__global__ void k_h0(const float* __restrict__ h_atom, const int* __restrict__ start,
                     float* __restrict__ hf32, uint16_t* __restrict__ hbf) {
  int g = blockIdx.x, t = threadIdx.x;             // 256 threads * 4 cols
  int s = start[g], e = start[g + 1];
  float m[4] = {-INFINITY, -INFINITY, -INFINITY, -INFINITY};
  const float* base = h_atom + t * 4;
  for (int a = s; a < e; a++) {
    float4 v = *(const float4*)(base + (size_t)a * H);
    m[0] = fmaxf(m[0], v.x); m[1] = fmaxf(m[1], v.y);
    m[2] = fmaxf(m[2], v.z); m[3] = fmaxf(m[3], v.w);
  }
  if (s == e) { m[0] = m[1] = m[2] = m[3] = 0.f; }
#pragma unroll
  for (int i = 0; i < 4; i++) {
    int c = t * 4 + i;
    float mv = m[i];
    uint16_t bv = f2bf(mv);
    hf32[(size_t)0 * GH + (size_t)g * H + c] = mv;     // [dir*2+buf][G][H], buf0
    hf32[(size_t)2 * GH + (size_t)g * H + c] = mv;
    hbf [(size_t)0 * GH + (size_t)g * H + c] = bv;
    hbf [(size_t)2 * GH + (size_t)g * H + c] = bv;
  }
}

// ---------------- xg = msg @ [Wf; Wb]^T  -> (N, 6144) bf16 ----------------
// 128x128 tile, BK=64, stride-72 LDS (bank-conflict pad), LDS-transpose epilogue.
__global__ __launch_bounds__(256) void k_gemm_xg(
    const uint16_t* __restrict__ A, const uint16_t* __restrict__ Wf,
    const uint16_t* __restrict__ Wb, uint16_t* __restrict__ C, int N) {
  __shared__ __align__(16) uint16_t smem[2 * 128 * 72];    // As | Bs; Cs aliases all
  uint16_t* As = smem;
  uint16_t* Bs = smem + 128 * 72;
  int bn = blockIdx.x, bm = blockIdx.y;            // bn 0..47, bm 0..N/128-1
  const uint16_t* B = (bn < 24) ? Wf : Wb;
  int brow = (bn < 24 ? bn : bn - 24) * 128;
  int tid = threadIdx.x, wid = tid >> 6, lane = tid & 63;
  int wm = wid >> 1, wn = wid & 1;
  floatx4 acc[4][4];
#pragma unroll
  for (int mi = 0; mi < 4; mi++)
#pragma unroll
    for (int ni = 0; ni < 4; ni++) acc[mi][ni] = (floatx4){0.f, 0.f, 0.f, 0.f};
  int arow = bm * 128;
  for (int kb = 0; kb < H; kb += 64) {
    uint4 av[4], bv[4];
#pragma unroll
    for (int p = 0; p < 4; p++) {                  // chunk c: row c>>3, k-off (c&7)*8
      int c = p * 256 + tid;
      av[p] = *(const uint4*)(A + (size_t)(arow + (c >> 3)) * H + kb + (c & 7) * 8);
      bv[p] = *(const uint4*)(B + (size_t)(brow + (c >> 3)) * H + kb + (c & 7) * 8);
    }
    __syncthreads();                               // prior iter's LDS reads done
#pragma unroll
    for (int p = 0; p < 4; p++) {
      int c = p * 256 + tid;
      *(uint4*)(As + (c >> 3) * 72 + (c & 7) * 8) = av[p];
      *(uint4*)(Bs + (c >> 3) * 72 + (c & 7) * 8) = bv[p];
    }
    __syncthreads();
#pragma unroll
    for (int ks = 0; ks < 2; ks++) {
      const uint16_t* ab = As + (wm * 64 + (lane & 15)) * 72 + ks * 32 + (lane >> 4) * 8;
      const uint16_t* bb = Bs + (wn * 64 + (lane & 15)) * 72 + ks * 32 + (lane >> 4) * 8;
      shortx8 af[4], bfr[4];
#pragma unroll
      for (int i = 0; i < 4; i++) {
        af[i]  = *(const shortx8*)(ab + i * 16 * 72);
        bfr[i] = *(const shortx8*)(bb + i * 16 * 72);
      }
#pragma unroll
      for (int mi = 0; mi < 4; mi++)
#pragma unroll
        for (int ni = 0; ni < 4; ni++)
          acc[mi][ni] = MFMA(af[mi], bfr[ni], acc[mi][ni]);
    }
  }
  __syncthreads();                                 // all MFMA LDS reads done
  // epilogue: acc -> LDS (row-major, stride 136) -> coalesced 16B global stores
  uint16_t* Cs = smem;                             // 128*136 = 17408 elems, fits
#pragma unroll
  for (int mi = 0; mi < 4; mi++)
#pragma unroll
    for (int ni = 0; ni < 4; ni++) {
      int row0 = wm * 64 + mi * 16 + (lane >> 4) * 4;
      int col  = wn * 64 + ni * 16 + (lane & 15);
#pragma unroll
      for (int r = 0; r < 4; r++) Cs[(row0 + r) * 136 + col] = f2bf(acc[mi][ni][r]);
    }
  __syncthreads();
#pragma unroll
  for (int p = 0; p < 8; p++) {
    int flat = p * 256 + tid;                      // 2048 16-B chunks
    int row = flat >> 4, ch = flat & 15;
    *(uint4*)(C + (size_t)(arow + row) * 6144 + bn * 128 + ch * 8) =
        *(const uint4*)(Cs + row * 136 + ch * 8);
  }
}

// ---------------- persistent bidirectional GRU scan ----------------
// grid=256, 1 wg/CU (LDS-forced). wg = (gh, d, jc): 128 graphs x 16 h-cols x dir.
// Weights (48 rows x 1024) resident in LDS across all 128 steps; h in registers;
// h exchanged via global bf16 buffer + all-to-all flag barrier per step.
__global__ __launch_bounds__(256, 1) void k_persist(
    const uint16_t* __restrict__ xg,
    const uint16_t* __restrict__ whhf, const uint16_t* __restrict__ whhb,
    const float* __restrict__ bihf, const float* __restrict__ bhhf,
    const float* __restrict__ bihb, const float* __restrict__ bhhb,
    const float* __restrict__ hf32, uint16_t* __restrict__ hbf,
    const int* __restrict__ start, float* __restrict__ out,
    int* __restrict__ flags) {
  __shared__ __align__(16) uint16_t Ws[48 * 1032];         // 99072 B, stride-pad 8
  __shared__ __align__(16) uint16_t As[2 * 128 * 72];      // 36864 B, double-buffered
  int b = blockIdx.x;
  int jc = b & 63, d = (b >> 6) & 1, gh = b >> 7;
  int tid = threadIdx.x, wid = tid >> 6, lane = tid & 63;
  const uint16_t* W = d ? whhb : whhf;
  const float* bih = d ? bihb : bihf;
  const float* bhh = d ? bhhb : bhhf;
  int col16 = lane & 15;
  int col = jc * 16 + col16;

  // --- load weight slice into LDS: LDS row q*16+rr <- W row q*1024 + jc*16 + rr ---
#pragma unroll
  for (int p = 0; p < 24; p++) {
    int flat = p * 256 + tid;                      // 6144 16-B chunks
    int row = flat >> 7, ch = flat & 127;
    *(uint4*)(Ws + row * 1032 + ch * 8) =
        *(const uint4*)(W + (size_t)((row >> 4) * H + jc * 16 + (row & 15)) * H + ch * 8);
  }

  // --- per-lane state: 8 (m,r) slots = 8 graph rows at this col ---
  float hreg[8], bihv[3], bhhv[3];
  int sg[8], cntg[8], gar[8];
#pragma unroll
  for (int q = 0; q < 3; q++) { bihv[q] = bih[q * H + col]; bhhv[q] = bhh[q * H + col]; }
#pragma unroll
  for (int m = 0; m < 2; m++)
#pragma unroll
    for (int r = 0; r < 4; r++) {
      int sl = m * 4 + r;
      int grow = wid * 32 + m * 16 + (lane >> 4) * 4 + r;
      int g = gh * 128 + grow;
      gar[sl] = g;
      sg[sl] = start[g];
      cntg[sl] = start[g + 1] - sg[sl];
      hreg[sl] = hf32[(size_t)(d * 2) * GH + (size_t)g * H + col];
    }
  __syncthreads();

  const int abase = wid * 32 + (lane & 15);        // A-frag row base within wg tile
  const int koff = (lane >> 4) * 8;

  for (int t = 0; t < LPAD; t++) {
    int cur = t & 1;
    const uint16_t* hsrc = hbf + (size_t)(d * 2 + cur) * GH + (size_t)gh * 128 * H;
    size_t ndst = (size_t)(d * 2 + (cur ^ 1)) * GH;
    floatx4 acc[2][3];
#pragma unroll
    for (int m = 0; m < 2; m++)
#pragma unroll
      for (int n = 0; n < 3; n++) acc[m][n] = (floatx4){0.f, 0.f, 0.f, 0.f};

    uint4 areg[4];
#pragma unroll
    for (int p = 0; p < 4; p++) {                  // prefetch kb=0
      int c = p * 256 + tid;
      areg[p] = *(const uint4*)(hsrc + (size_t)(c >> 3) * H + (c & 7) * 8);
    }
    for (int kb = 0; kb < 16; kb++) {
      uint16_t* Ab = As + (kb & 1) * (128 * 72);
#pragma unroll
      for (int p = 0; p < 4; p++) {
        int c = p * 256 + tid;
        *(uint4*)(Ab + (c >> 3) * 72 + (c & 7) * 8) = areg[p];
      }
      __syncthreads();
      if (kb < 15) {
#pragma unroll
        for (int p = 0; p < 4; p++) {              // prefetch kb+1 (overlaps MFMA)
          int c = p * 256 + tid;
          areg[p] = *(const uint4*)(hsrc + (size_t)(c >> 3) * H + (kb + 1) * 64 + (c & 7) * 8);
        }
      }
      const uint16_t* ab = Ab + abase * 72 + koff;
      const uint16_t* wb = Ws + (lane & 15) * 1032 + kb * 64 + koff;
#pragma unroll
      for (int ks = 0; ks < 2; ks++) {
        shortx8 a0 = *(const shortx8*)(ab + ks * 32);
        shortx8 a1 = *(const shortx8*)(ab + 16 * 72 + ks * 32);
#pragma unroll
        for (int n = 0; n < 3; n++) {
          shortx8 bv = *(const shortx8*)(wb + n * 16 * 1032 + ks * 32);
          acc[0][n] = MFMA(a0, bv, acc[0][n]);
          acc[1][n] = MFMA(a1, bv, acc[1][n]);
        }
      }
      // no trailing sync: next iter writes the other As buffer
    }

    // --- gates: the (r,z,n) triple for (g,col) sits in acc[m][0..2][r] of this lane ---
#pragma unroll
    for (int m = 0; m < 2; m++)
#pragma unroll
      for (int r = 0; r < 4; r++) {
        int sl = m * 4 + r;
        int t_g = d ? (LPAD - 1 - t) : t;
        bool act = t_g < cntg[sl];
        float xr = 0.f, xz = 0.f, xn = 0.f;
        if (act) {
          const uint16_t* xp = xg + (size_t)(sg[sl] + t_g) * 6144 + d * 3072 + col;
          xr = bf2f(xp[0]); xz = bf2f(xp[H]); xn = bf2f(xp[2 * H]);
        }
        float rv = sigmoid_(xr + bihv[0] + acc[m][0][r] + bhhv[0]);
        float zv = sigmoid_(xz + bihv[1] + acc[m][1][r] + bhhv[1]);
        float nv = tanh_(xn + bihv[2] + rv * (acc[m][2][r] + bhhv[2]));
        float hnew = (1.f - zv) * nv + zv * hreg[sl];
        hreg[sl] = hnew;
        hbf[ndst + (size_t)gar[sl] * H + col] = f2bf(hnew);
        if (act) out[(size_t)(sg[sl] + t_g) * 2048 + d * H + col] = hnew;
      }

    // --- grid barrier (all-to-all flags, agent scope) ---
    if (t < LPAD - 1) {
      __threadfence();                             // drain own stores, device scope
      __syncthreads();
      if (tid == 0)
        __hip_atomic_store(&flags[b], t + 1, __ATOMIC_RELEASE, __HIP_MEMORY_SCOPE_AGENT);
      while (__hip_atomic_load(&flags[tid], __ATOMIC_ACQUIRE, __HIP_MEMORY_SCOPE_AGENT) < t + 1)
        __builtin_amdgcn_s_sleep(2);
      __syncthreads();
    }
  }
}

extern "C" void kernel_launch(void* const* d_in, const int* in_sizes, int n_in,
                              void* d_out, int out_size, void* d_ws, size_t ws_size,
                              hipStream_t stream) {
  const float* h_atom = (const float*)d_in[0];
  const int*   batch  = (const int*)d_in[1];
  const float* bias   = (const float*)d_in[2];
  const float* w_ih_f = (const float*)d_in[3];
  const float* w_hh_f = (const float*)d_in[4];
  const float* b_ih_f = (const float*)d_in[5];
  const float* b_hh_f = (const float*)d_in[6];
  const float* w_ih_b = (const float*)d_in[7];
  const float* w_hh_b = (const float*)d_in[8];
  const float* b_ih_b = (const float*)d_in[9];
  const float* b_hh_b = (const float*)d_in[10];
  int N = in_sizes[0] / H;                          // 16384
  float* out = (float*)d_out;

  const size_t W3 = (size_t)3 * H * H;
  char* ws = (char*)d_ws;
  uint16_t* msg  = (uint16_t*)ws;                           // N*H bf16
  uint16_t* xg   = (uint16_t*)(ws + (size_t)N * H * 2);     // N*6144 bf16
  char* p = ws + (size_t)N * H * 2 + (size_t)N * 6144 * 2;
  uint16_t* wihf = (uint16_t*)p; p += W3 * 2;
  uint16_t* wihb = (uint16_t*)p; p += W3 * 2;
  uint16_t* whhf = (uint16_t*)p; p += W3 * 2;
  uint16_t* whhb = (uint16_t*)p; p += W3 * 2;
  float*    hf32 = (float*)p;    p += (size_t)4 * GH * 4;   // [dir*2+buf][G][H]
  uint16_t* hbf  = (uint16_t*)p; p += (size_t)4 * GH * 2;
  int*      start = (int*)p;     p += 1024;                 // 257 ints (padded)
  int*      flags = (int*)p;                                // 256 ints

  int wgrid = (int)(W3 / (256 * 8));                // 1536
  k_f2b<<<wgrid, 256, 0, stream>>>(w_ih_f, wihf);
  k_f2b<<<wgrid, 256, 0, stream>>>(w_ih_b, wihb);
  k_f2b<<<wgrid, 256, 0, stream>>>(w_hh_f, whhf);
  k_f2b<<<wgrid, 256, 0, stream>>>(w_hh_b, whhb);
  k_setup<<<1, 512, 0, stream>>>(batch, N, start, flags);
  k_msg<<<N, 128, 0, stream>>>(h_atom, bias, msg);
  k_h0<<<G_, 256, 0, stream>>>(h_atom, start, hf32, hbf);
  k_gemm_xg<<<dim3(48, N / 128), 256, 0, stream>>>(msg, wihf, wihb, xg, N);
  k_persist<<<256, 256, 0, stream>>>(xg, whhf, whhb, b_ih_f, b_hh_f, b_ih_b, b_hh_b,
                                     hf32, hbf, start, out, flags);
}